// Round 1
// baseline (2146.110 us; speedup 1.0000x reference)
//
#include <hip/hip_runtime.h>
#include <cstdint>
#include <cstddef>

#define NFEAT 256
#define NCLS  16

// ---------------------------------------------------------------------------
// Graph build
// ---------------------------------------------------------------------------
__global__ void k_count(const int* __restrict__ dst, int* __restrict__ counts, int E) {
    int i = blockIdx.x * 256 + threadIdx.x;
    if (i < E) atomicAdd(&counts[dst[i]], 1);
}

__global__ void k_dis(const int* __restrict__ counts, float* __restrict__ dis, int Nn) {
    int i = blockIdx.x * 256 + threadIdx.x;
    if (i < Nn) dis[i] = rsqrtf((float)(counts[i] + 1));   // deg = in-deg + self-loop >= 1
}

// single-block exclusive scan of counts -> rowptr (and cursor copy)
__global__ __launch_bounds__(256) void k_scan(const int* __restrict__ counts,
                                              int* __restrict__ rowptr,
                                              int* __restrict__ cursor, int Nn) {
    int t = threadIdx.x;
    int CH = (Nn + 255) / 256;
    int i0 = t * CH, i1 = min(i0 + CH, Nn);
    int s = 0;
    for (int i = i0; i < i1; ++i) s += counts[i];
    __shared__ int ps[256];
    ps[t] = s;
    __syncthreads();
    for (int off = 1; off < 256; off <<= 1) {
        int v = (t >= off) ? ps[t - off] : 0;
        __syncthreads();
        ps[t] += v;
        __syncthreads();
    }
    int run = (t == 0) ? 0 : ps[t - 1];
    for (int i = i0; i < i1; ++i) {
        rowptr[i] = run;
        cursor[i] = run;
        run += counts[i];
    }
    if (t == 255) rowptr[Nn] = ps[255];
}

__global__ void k_fill(const int* __restrict__ src, const int* __restrict__ dst,
                       const float* __restrict__ dis, int* __restrict__ cursor,
                       int* __restrict__ csr_col, float* __restrict__ csr_val, int E) {
    int i = blockIdx.x * 256 + threadIdx.x;
    if (i < E) {
        int s = src[i], d = dst[i];
        int pos = atomicAdd(&cursor[d], 1);
        csr_col[pos] = s;
        csr_val[pos] = dis[s];
    }
}

// ---------------------------------------------------------------------------
// fp32 GEMM: C[M,256] = A[M,256] @ W[256,256].  BM=BN=128, BK=16, 256 thr.
// ---------------------------------------------------------------------------
__global__ __launch_bounds__(256) void gemm128(const float* __restrict__ A,
                                               const float* __restrict__ W,
                                               float* __restrict__ C, int M) {
    const int K = NFEAT;
    __shared__ float As[16][128];
    __shared__ float Bs[16][128];
    int t  = threadIdx.x;
    int bm = blockIdx.x * 128;
    int bn = blockIdx.y * 128;
    int tx = t & 15, ty = t >> 4;
    int am = t & 127;            // A tile row this thread loads
    int ak = (t >> 7) * 8;       // k offset 0 or 8
    int bn4 = (t & 31) * 4;      // B tile col (x4)
    int bk  = t >> 5;            // B tile k rows bk, bk+8

    float acc[8][8];
#pragma unroll
    for (int i = 0; i < 8; ++i)
#pragma unroll
        for (int j = 0; j < 8; ++j) acc[i][j] = 0.f;

    int arow = bm + am;
    bool avalid = arow < M;
    const float* Aptr = A + (size_t)(avalid ? arow : 0) * K;

    for (int k0 = 0; k0 < K; k0 += 16) {
        float4 a0 = make_float4(0.f, 0.f, 0.f, 0.f), a1 = a0;
        if (avalid) {
            a0 = *(const float4*)(Aptr + k0 + ak);
            a1 = *(const float4*)(Aptr + k0 + ak + 4);
        }
        float4 w0 = *(const float4*)(W + (size_t)(k0 + bk)     * NFEAT + bn + bn4);
        float4 w1 = *(const float4*)(W + (size_t)(k0 + bk + 8) * NFEAT + bn + bn4);
        __syncthreads();
        As[ak + 0][am] = a0.x; As[ak + 1][am] = a0.y;
        As[ak + 2][am] = a0.z; As[ak + 3][am] = a0.w;
        As[ak + 4][am] = a1.x; As[ak + 5][am] = a1.y;
        As[ak + 6][am] = a1.z; As[ak + 7][am] = a1.w;
        *(float4*)&Bs[bk][bn4]     = w0;
        *(float4*)&Bs[bk + 8][bn4] = w1;
        __syncthreads();
#pragma unroll
        for (int kk = 0; kk < 16; ++kk) {
            float4 fa0 = *(const float4*)&As[kk][ty * 4];
            float4 fa1 = *(const float4*)&As[kk][ty * 4 + 64];
            float4 fb0 = *(const float4*)&Bs[kk][tx * 4];
            float4 fb1 = *(const float4*)&Bs[kk][tx * 4 + 64];
            float av[8] = {fa0.x, fa0.y, fa0.z, fa0.w, fa1.x, fa1.y, fa1.z, fa1.w};
            float bv[8] = {fb0.x, fb0.y, fb0.z, fb0.w, fb1.x, fb1.y, fb1.z, fb1.w};
#pragma unroll
            for (int i = 0; i < 8; ++i)
#pragma unroll
                for (int j = 0; j < 8; ++j)
                    acc[i][j] = fmaf(av[i], bv[j], acc[i][j]);
        }
    }
#pragma unroll
    for (int i = 0; i < 8; ++i) {
        int r = bm + ty * 4 + (i >> 2) * 64 + (i & 3);
        if (r < M) {
            float* cp = C + (size_t)r * NFEAT + bn + tx * 4;
            *(float4*)cp        = make_float4(acc[i][0], acc[i][1], acc[i][2], acc[i][3]);
            *(float4*)(cp + 64) = make_float4(acc[i][4], acc[i][5], acc[i][6], acc[i][7]);
        }
    }
}

// ---------------------------------------------------------------------------
// Propagation, 256-wide rows: out[d] = dis_d*(sum_e val_e*y[col_e]) + dis_d^2*y[d] + b
// one block per dst node, thread = feature column
// ---------------------------------------------------------------------------
__global__ __launch_bounds__(256) void k_agg256(const float* __restrict__ y,
                                                const int* __restrict__ rowptr,
                                                const int* __restrict__ col,
                                                const float* __restrict__ val,
                                                const float* __restrict__ dis,
                                                const float* __restrict__ bias,
                                                float* __restrict__ out) {
    int d = blockIdx.x;
    int c = threadIdx.x;
    int beg = rowptr[d], end = rowptr[d + 1];
    float acc0 = 0.f, acc1 = 0.f, acc2 = 0.f, acc3 = 0.f;
    int e = beg;
    for (; e + 3 < end; e += 4) {
        int   c0 = col[e],     c1 = col[e + 1], c2 = col[e + 2], c3 = col[e + 3];
        float v0 = val[e],     v1 = val[e + 1], v2 = val[e + 2], v3 = val[e + 3];
        acc0 = fmaf(v0, y[(size_t)c0 * NFEAT + c], acc0);
        acc1 = fmaf(v1, y[(size_t)c1 * NFEAT + c], acc1);
        acc2 = fmaf(v2, y[(size_t)c2 * NFEAT + c], acc2);
        acc3 = fmaf(v3, y[(size_t)c3 * NFEAT + c], acc3);
    }
    for (; e < end; ++e)
        acc0 = fmaf(val[e], y[(size_t)col[e] * NFEAT + c], acc0);
    float dd = dis[d];
    float r = dd * ((acc0 + acc1) + (acc2 + acc3)) + dd * dd * y[(size_t)d * NFEAT + c];
    out[(size_t)d * NFEAT + c] = r + bias[c];
}

// ---------------------------------------------------------------------------
// final layer: Y[M,16] = relu(A[M,256]) @ W2[256,16]
// ---------------------------------------------------------------------------
__global__ __launch_bounds__(256) void k_gemm16(const float* __restrict__ A,
                                                const float* __restrict__ W2,
                                                float* __restrict__ Y, int M) {
    __shared__ float Ws[256][16];
    int t = threadIdx.x;
    for (int i = t; i < 256 * 16; i += 256) Ws[i >> 4][i & 15] = W2[i];
    __syncthreads();
    int tx = t & 15, ty = t >> 4;
    int r = blockIdx.x * 16 + ty;
    if (r >= M) return;
    const float* a = A + (size_t)r * NFEAT;
    float acc = 0.f;
    for (int k = 0; k < 256; k += 4) {
        float4 av = *(const float4*)(a + k);
        av.x = fmaxf(av.x, 0.f); av.y = fmaxf(av.y, 0.f);
        av.z = fmaxf(av.z, 0.f); av.w = fmaxf(av.w, 0.f);
        acc = fmaf(av.x, Ws[k][tx], acc);
        acc = fmaf(av.y, Ws[k + 1][tx], acc);
        acc = fmaf(av.z, Ws[k + 2][tx], acc);
        acc = fmaf(av.w, Ws[k + 3][tx], acc);
    }
    Y[(size_t)r * NCLS + tx] = acc;
}

// propagation at width 16: block = 16 nodes x 16 cols
__global__ __launch_bounds__(256) void k_agg16(const float* __restrict__ y16,
                                               const int* __restrict__ rowptr,
                                               const int* __restrict__ col,
                                               const float* __restrict__ val,
                                               const float* __restrict__ dis,
                                               const float* __restrict__ b2,
                                               float* __restrict__ out, int Nn) {
    int t = threadIdx.x;
    int tx = t & 15, ty = t >> 4;
    int d = blockIdx.x * 16 + ty;
    if (d >= Nn) return;
    int beg = rowptr[d], end = rowptr[d + 1];
    float acc = 0.f;
    for (int e = beg; e < end; ++e)
        acc = fmaf(val[e], y16[(size_t)col[e] * NCLS + tx], acc);
    float dd = dis[d];
    out[(size_t)d * NCLS + tx] = dd * acc + dd * dd * y16[(size_t)d * NCLS + tx] + b2[tx];
}

// ---------------------------------------------------------------------------
// softmax over axis 0 (over the 100k nodes, per class)
// ---------------------------------------------------------------------------
__global__ __launch_bounds__(256) void k_sm1(const float* __restrict__ z,
                                             float* __restrict__ pmax,
                                             float* __restrict__ psum, int Nn) {
    int b = blockIdx.x, t = threadIdx.x, tx = t & 15, ty = t >> 4;
    int CH = (Nn + 255) / 256;
    int r0 = b * CH, r1 = min(r0 + CH, Nn);
    __shared__ float red[16][17];
    __shared__ float gloc[16];
    float m = -3.4e38f;
    for (int r = r0 + ty; r < r1; r += 16) m = fmaxf(m, z[(size_t)r * NCLS + tx]);
    red[ty][tx] = m;
    __syncthreads();
    if (ty == 0) {
        float mm = red[0][tx];
#pragma unroll
        for (int i = 1; i < 16; ++i) mm = fmaxf(mm, red[i][tx]);
        gloc[tx] = mm;
    }
    __syncthreads();
    float g = gloc[tx];
    float s = 0.f;
    for (int r = r0 + ty; r < r1; r += 16) s += expf(z[(size_t)r * NCLS + tx] - g);
    red[ty][tx] = s;
    __syncthreads();
    if (ty == 0) {
        float ss = red[0][tx];
#pragma unroll
        for (int i = 1; i < 16; ++i) ss += red[i][tx];
        pmax[b * 16 + tx] = g;
        psum[b * 16 + tx] = ss;
    }
}

__global__ __launch_bounds__(256) void k_sm2(const float* __restrict__ pmax,
                                             const float* __restrict__ psum,
                                             float* __restrict__ g16,
                                             float* __restrict__ inv16) {
    int t = threadIdx.x, tx = t & 15, ty = t >> 4;
    __shared__ float red[16][17];
    __shared__ float gsh[16];
    float m = -3.4e38f;
    for (int b = ty; b < 256; b += 16) m = fmaxf(m, pmax[b * 16 + tx]);
    red[ty][tx] = m;
    __syncthreads();
    if (ty == 0) {
        float mm = red[0][tx];
#pragma unroll
        for (int i = 1; i < 16; ++i) mm = fmaxf(mm, red[i][tx]);
        gsh[tx] = mm;
    }
    __syncthreads();
    float g = gsh[tx];
    float s = 0.f;
    for (int b = ty; b < 256; b += 16)
        s += psum[b * 16 + tx] * expf(pmax[b * 16 + tx] - g);
    red[ty][tx] = s;
    __syncthreads();
    if (ty == 0) {
        float ss = red[0][tx];
#pragma unroll
        for (int i = 1; i < 16; ++i) ss += red[i][tx];
        g16[tx] = g;
        inv16[tx] = 1.0f / ss;
    }
}

__global__ void k_sm5(float* __restrict__ z, const float* __restrict__ g16,
                      const float* __restrict__ inv16, int total) {
    int i = blockIdx.x * 256 + threadIdx.x;
    if (i < total) {
        int c = i & 15;
        z[i] = expf(z[i] - g16[c]) * inv16[c];
    }
}

// ---------------------------------------------------------------------------
extern "C" void kernel_launch(void* const* d_in, const int* in_sizes, int n_in,
                              void* d_out, int out_size, void* d_ws, size_t ws_size,
                              hipStream_t stream) {
    const float* x  = (const float*)d_in[0];
    const int*   ei = (const int*)d_in[1];
    const float* W1 = (const float*)d_in[2];
    const float* b1 = (const float*)d_in[3];
    const float* Wi = (const float*)d_in[4];
    const float* bi = (const float*)d_in[5];
    const float* W2 = (const float*)d_in[6];
    const float* b2 = (const float*)d_in[7];
    float* out = (float*)d_out;

    int Nn = in_sizes[0] / NFEAT;   // 100000
    int E  = in_sizes[1] / 2;       // 1600000
    const int* esrc = ei;
    const int* edst = ei + E;

    char* p = (char*)d_ws;
    auto carve = [&](size_t bytes) -> char* {
        char* r = p;
        p += (bytes + 255) / 256 * 256;
        return r;
    };
    float* bufA    = (float*)carve((size_t)Nn * NFEAT * 4);
    float* bufB    = (float*)carve((size_t)Nn * NFEAT * 4);
    int*   counts  = (int*)  carve((size_t)Nn * 4);
    int*   cursor  = (int*)  carve((size_t)Nn * 4);
    int*   rowptr  = (int*)  carve((size_t)(Nn + 1) * 4);
    float* dis     = (float*)carve((size_t)Nn * 4);
    int*   csr_col = (int*)  carve((size_t)E * 4);
    float* csr_val = (float*)carve((size_t)E * 4);
    float* y16     = (float*)carve((size_t)Nn * NCLS * 4);
    float* pmax    = (float*)carve(256 * 16 * 4);
    float* psum    = (float*)carve(256 * 16 * 4);
    float* g16     = (float*)carve(16 * 4);
    float* inv16   = (float*)carve(16 * 4);

    hipMemsetAsync(counts, 0, (size_t)Nn * 4, stream);

    int gE = (E + 255) / 256;
    k_count<<<gE, 256, 0, stream>>>(edst, counts, E);
    k_dis<<<(Nn + 255) / 256, 256, 0, stream>>>(counts, dis, Nn);
    k_scan<<<1, 256, 0, stream>>>(counts, rowptr, cursor, Nn);
    k_fill<<<gE, 256, 0, stream>>>(esrc, edst, dis, cursor, csr_col, csr_val, E);

    dim3 gg((Nn + 127) / 128, NFEAT / 128);
    gemm128<<<gg, 256, 0, stream>>>(x, W1, bufB, Nn);
    k_agg256<<<Nn, 256, 0, stream>>>(bufB, rowptr, csr_col, csr_val, dis, b1, bufA);
    for (int it = 0; it < 3; ++it) {
        gemm128<<<gg, 256, 0, stream>>>(bufA, Wi, bufB, Nn);
        k_agg256<<<Nn, 256, 0, stream>>>(bufB, rowptr, csr_col, csr_val, dis, bi, bufA);
    }
    int g16b = (Nn + 15) / 16;
    k_gemm16<<<g16b, 256, 0, stream>>>(bufA, W2, y16, Nn);
    k_agg16<<<g16b, 256, 0, stream>>>(y16, rowptr, csr_col, csr_val, dis, b2, out, Nn);

    k_sm1<<<256, 256, 0, stream>>>(out, pmax, psum, Nn);
    k_sm2<<<1, 256, 0, stream>>>(pmax, psum, g16, inv16);
    k_sm5<<<(Nn * NCLS + 255) / 256, 256, 0, stream>>>(out, g16, inv16, Nn * NCLS);
}

// Round 2
// 1295.292 us; speedup vs baseline: 1.6569x; 1.6569x over previous
//
#include <hip/hip_runtime.h>
#include <cstdint>
#include <cstddef>

#define NFEAT 256
#define NCLS  16

typedef unsigned int uint;
typedef unsigned short ushort;

__device__ inline float blo(uint u) { return __uint_as_float(u << 16); }
__device__ inline float bhi(uint u) { return __uint_as_float(u & 0xffff0000u); }
__device__ inline ushort f2bf(float f) {
    uint b = __float_as_uint(f);
    b += 0x7fffu + ((b >> 16) & 1u);
    return (ushort)(b >> 16);
}
__device__ inline uint pack2(float a, float b) {
    return (uint)f2bf(a) | ((uint)f2bf(b) << 16);
}

// ---------------------------------------------------------------------------
// Graph build
// ---------------------------------------------------------------------------
__global__ void k_count(const int* __restrict__ dst, int* __restrict__ counts, int E) {
    int i = blockIdx.x * 256 + threadIdx.x;
    if (i < E) atomicAdd(&counts[dst[i]], 1);
}

__global__ void k_dis(const int* __restrict__ counts, float* __restrict__ dis, int Nn) {
    int i = blockIdx.x * 256 + threadIdx.x;
    if (i < Nn) dis[i] = rsqrtf((float)(counts[i] + 1));
}

__global__ __launch_bounds__(256) void k_scan(const int* __restrict__ counts,
                                              int* __restrict__ rowptr,
                                              int* __restrict__ cursor, int Nn) {
    int t = threadIdx.x;
    int CH = (Nn + 255) / 256;
    int i0 = t * CH, i1 = min(i0 + CH, Nn);
    int s = 0;
    for (int i = i0; i < i1; ++i) s += counts[i];
    __shared__ int ps[256];
    ps[t] = s;
    __syncthreads();
    for (int off = 1; off < 256; off <<= 1) {
        int v = (t >= off) ? ps[t - off] : 0;
        __syncthreads();
        ps[t] += v;
        __syncthreads();
    }
    int run = (t == 0) ? 0 : ps[t - 1];
    for (int i = i0; i < i1; ++i) {
        rowptr[i] = run;
        cursor[i] = run;
        run += counts[i];
    }
    if (t == 255) rowptr[Nn] = ps[255];
}

__global__ void k_fill(const int* __restrict__ src, const int* __restrict__ dst,
                       const float* __restrict__ dis, int* __restrict__ cursor,
                       int* __restrict__ csr_col, float* __restrict__ csr_val, int E) {
    int i = blockIdx.x * 256 + threadIdx.x;
    if (i < E) {
        int s = src[i], d = dst[i];
        int pos = atomicAdd(&cursor[d], 1);
        csr_col[pos] = s;
        csr_val[pos] = dis[s];
    }
}

// ---------------------------------------------------------------------------
// small dense helpers: 256x256 @ 256x256, and vec256 @ 256x256
// ---------------------------------------------------------------------------
__global__ __launch_bounds__(256) void k_mm256(const float* __restrict__ A,
                                               const float* __restrict__ B,
                                               float* __restrict__ C) {
    int i = blockIdx.x, j = threadIdx.x;
    float acc = 0.f;
    for (int k = 0; k < 256; ++k) acc = fmaf(A[i * 256 + k], B[k * 256 + j], acc);
    C[i * 256 + j] = acc;
}

__global__ __launch_bounds__(256) void k_vm256(const float* __restrict__ v,
                                               const float* __restrict__ M,
                                               float* __restrict__ r) {
    int j = threadIdx.x;
    float acc = 0.f;
    for (int k = 0; k < 256; ++k) acc = fmaf(v[k], M[(size_t)k * 256 + j], acc);
    r[j] = acc;
}

// scalar propagation: sout = A_hat * sin   (FIRST: sin == ones)
template <int FIRST>
__global__ __launch_bounds__(256) void k_svec(const float* __restrict__ sin,
                                              const int* __restrict__ rowptr,
                                              const int* __restrict__ col,
                                              const float* __restrict__ val,
                                              const float* __restrict__ dis,
                                              float* __restrict__ sout, int Nn) {
    int d = blockIdx.x * 256 + threadIdx.x;
    if (d >= Nn) return;
    int beg = rowptr[d], end = rowptr[d + 1];
    float acc = 0.f;
    if (FIRST) {
        for (int e = beg; e < end; ++e) acc += val[e];
    } else {
        for (int e = beg; e < end; ++e) acc = fmaf(val[e], sin[col[e]], acc);
    }
    float dd = dis[d];
    sout[d] = fmaf(dd, acc, dd * dd * (FIRST ? 1.f : sin[d]));
}

// ---------------------------------------------------------------------------
// fp32 GEMM, bf16 output: C[M,256](bf16) = A[M,256](f32) @ W[256,256](f32)
// ---------------------------------------------------------------------------
__global__ __launch_bounds__(256) void gemm128b(const float* __restrict__ A,
                                                const float* __restrict__ W,
                                                ushort* __restrict__ C, int M) {
    const int K = NFEAT;
    __shared__ float As[16][128];
    __shared__ float Bs[16][128];
    int t  = threadIdx.x;
    int bm = blockIdx.x * 128;
    int bn = blockIdx.y * 128;
    int tx = t & 15, ty = t >> 4;
    int am = t & 127;
    int ak = (t >> 7) * 8;
    int bn4 = (t & 31) * 4;
    int bk  = t >> 5;

    float acc[8][8];
#pragma unroll
    for (int i = 0; i < 8; ++i)
#pragma unroll
        for (int j = 0; j < 8; ++j) acc[i][j] = 0.f;

    int arow = bm + am;
    bool avalid = arow < M;
    const float* Aptr = A + (size_t)(avalid ? arow : 0) * K;

    for (int k0 = 0; k0 < K; k0 += 16) {
        float4 a0 = make_float4(0.f, 0.f, 0.f, 0.f), a1 = a0;
        if (avalid) {
            a0 = *(const float4*)(Aptr + k0 + ak);
            a1 = *(const float4*)(Aptr + k0 + ak + 4);
        }
        float4 w0 = *(const float4*)(W + (size_t)(k0 + bk)     * NFEAT + bn + bn4);
        float4 w1 = *(const float4*)(W + (size_t)(k0 + bk + 8) * NFEAT + bn + bn4);
        __syncthreads();
        As[ak + 0][am] = a0.x; As[ak + 1][am] = a0.y;
        As[ak + 2][am] = a0.z; As[ak + 3][am] = a0.w;
        As[ak + 4][am] = a1.x; As[ak + 5][am] = a1.y;
        As[ak + 6][am] = a1.z; As[ak + 7][am] = a1.w;
        *(float4*)&Bs[bk][bn4]     = w0;
        *(float4*)&Bs[bk + 8][bn4] = w1;
        __syncthreads();
#pragma unroll
        for (int kk = 0; kk < 16; ++kk) {
            float4 fa0 = *(const float4*)&As[kk][ty * 4];
            float4 fa1 = *(const float4*)&As[kk][ty * 4 + 64];
            float4 fb0 = *(const float4*)&Bs[kk][tx * 4];
            float4 fb1 = *(const float4*)&Bs[kk][tx * 4 + 64];
            float av[8] = {fa0.x, fa0.y, fa0.z, fa0.w, fa1.x, fa1.y, fa1.z, fa1.w};
            float bv[8] = {fb0.x, fb0.y, fb0.z, fb0.w, fb1.x, fb1.y, fb1.z, fb1.w};
#pragma unroll
            for (int i = 0; i < 8; ++i)
#pragma unroll
                for (int j = 0; j < 8; ++j)
                    acc[i][j] = fmaf(av[i], bv[j], acc[i][j]);
        }
    }
#pragma unroll
    for (int i = 0; i < 8; ++i) {
        int r = bm + ty * 4 + (i >> 2) * 64 + (i & 3);
        if (r < M) {
            ushort* cp = C + (size_t)r * NFEAT + bn + tx * 4;
            ushort4 s0 = {f2bf(acc[i][0]), f2bf(acc[i][1]), f2bf(acc[i][2]), f2bf(acc[i][3])};
            ushort4 s1 = {f2bf(acc[i][4]), f2bf(acc[i][5]), f2bf(acc[i][6]), f2bf(acc[i][7])};
            *(ushort4*)cp        = s0;
            *(ushort4*)(cp + 64) = s1;
        }
    }
}

// ---------------------------------------------------------------------------
// bf16 propagation: out[d] = bf16( dis_d*sum(val*y[col]) + dis_d^2*y[d] [+rank1] )
// 64 threads = 1 wave per node; thread owns 4 features (one uint2 = 4 bf16)
// ---------------------------------------------------------------------------
template <int FINAL>
__global__ __launch_bounds__(64) void k_aggb(const uint* __restrict__ y,
                                             const int* __restrict__ rowptr,
                                             const int* __restrict__ col,
                                             const float* __restrict__ val,
                                             const float* __restrict__ dis,
                                             const float* __restrict__ s1,
                                             const float* __restrict__ s2,
                                             const float* __restrict__ s3,
                                             const float* __restrict__ c1,
                                             const float* __restrict__ c2,
                                             const float* __restrict__ c3,
                                             const float* __restrict__ c4,
                                             uint* __restrict__ out) {
    int d = blockIdx.x;
    int t = threadIdx.x;
    const uint* yt = y + 2 * t;          // this thread's 4 features of any row
    int beg = rowptr[d], end = rowptr[d + 1];
    float a0 = 0.f, a1 = 0.f, a2 = 0.f, a3 = 0.f;
    int e = beg;
    for (; e + 3 < end; e += 4) {
        int   cA = col[e],     cB = col[e + 1], cC = col[e + 2], cD = col[e + 3];
        float vA = val[e],     vB = val[e + 1], vC = val[e + 2], vD = val[e + 3];
        uint2 uA = *(const uint2*)(yt + (size_t)cA * 128);
        uint2 uB = *(const uint2*)(yt + (size_t)cB * 128);
        uint2 uC = *(const uint2*)(yt + (size_t)cC * 128);
        uint2 uD = *(const uint2*)(yt + (size_t)cD * 128);
        a0 = fmaf(vA, blo(uA.x), a0); a1 = fmaf(vA, bhi(uA.x), a1);
        a2 = fmaf(vA, blo(uA.y), a2); a3 = fmaf(vA, bhi(uA.y), a3);
        a0 = fmaf(vB, blo(uB.x), a0); a1 = fmaf(vB, bhi(uB.x), a1);
        a2 = fmaf(vB, blo(uB.y), a2); a3 = fmaf(vB, bhi(uB.y), a3);
        a0 = fmaf(vC, blo(uC.x), a0); a1 = fmaf(vC, bhi(uC.x), a1);
        a2 = fmaf(vC, blo(uC.y), a2); a3 = fmaf(vC, bhi(uC.y), a3);
        a0 = fmaf(vD, blo(uD.x), a0); a1 = fmaf(vD, bhi(uD.x), a1);
        a2 = fmaf(vD, blo(uD.y), a2); a3 = fmaf(vD, bhi(uD.y), a3);
    }
    for (; e < end; ++e) {
        int c = col[e]; float v = val[e];
        uint2 u = *(const uint2*)(yt + (size_t)c * 128);
        a0 = fmaf(v, blo(u.x), a0); a1 = fmaf(v, bhi(u.x), a1);
        a2 = fmaf(v, blo(u.y), a2); a3 = fmaf(v, bhi(u.y), a3);
    }
    float dd = dis[d];
    float d2 = dd * dd;
    uint2 us = *(const uint2*)(yt + (size_t)d * 128);
    float r0 = fmaf(dd, a0, d2 * blo(us.x));
    float r1 = fmaf(dd, a1, d2 * bhi(us.x));
    float r2 = fmaf(dd, a2, d2 * blo(us.y));
    float r3 = fmaf(dd, a3, d2 * bhi(us.y));
    if (FINAL) {
        float4 C1 = *(const float4*)(c1 + 4 * t);
        float4 C2 = *(const float4*)(c2 + 4 * t);
        float4 C3 = *(const float4*)(c3 + 4 * t);
        float4 C4 = *(const float4*)(c4 + 4 * t);
        float S1 = s1[d], S2 = s2[d], S3 = s3[d];
        r0 += S3 * C1.x + S2 * C2.x + S1 * C3.x + C4.x;
        r1 += S3 * C1.y + S2 * C2.y + S1 * C3.y + C4.y;
        r2 += S3 * C1.z + S2 * C2.z + S1 * C3.z + C4.z;
        r3 += S3 * C1.w + S2 * C2.w + S1 * C3.w + C4.w;
    }
    uint2 o;
    o.x = pack2(r0, r1);
    o.y = pack2(r2, r3);
    *(uint2*)(out + (size_t)d * 128 + 2 * t) = o;
}

// ---------------------------------------------------------------------------
// final layer: Y[M,16](f32) = relu(A[M,256](bf16)) @ W2[256,16](f32)
// ---------------------------------------------------------------------------
__global__ __launch_bounds__(256) void k_gemm16b(const uint* __restrict__ A,
                                                 const float* __restrict__ W2,
                                                 float* __restrict__ Y, int M) {
    __shared__ float Ws[256][16];
    int t = threadIdx.x;
    for (int i = t; i < 256 * 16; i += 256) Ws[i >> 4][i & 15] = W2[i];
    __syncthreads();
    int tx = t & 15, ty = t >> 4;
    int r = blockIdx.x * 16 + ty;
    if (r >= M) return;
    const uint* a = A + (size_t)r * 128;
    float acc = 0.f;
    for (int i = 0; i < 128; i += 4) {
        uint4 u = *(const uint4*)(a + i);
        float f;
        f = fmaxf(blo(u.x), 0.f); acc = fmaf(f, Ws[2 * i + 0][tx], acc);
        f = fmaxf(bhi(u.x), 0.f); acc = fmaf(f, Ws[2 * i + 1][tx], acc);
        f = fmaxf(blo(u.y), 0.f); acc = fmaf(f, Ws[2 * i + 2][tx], acc);
        f = fmaxf(bhi(u.y), 0.f); acc = fmaf(f, Ws[2 * i + 3][tx], acc);
        f = fmaxf(blo(u.z), 0.f); acc = fmaf(f, Ws[2 * i + 4][tx], acc);
        f = fmaxf(bhi(u.z), 0.f); acc = fmaf(f, Ws[2 * i + 5][tx], acc);
        f = fmaxf(blo(u.w), 0.f); acc = fmaf(f, Ws[2 * i + 6][tx], acc);
        f = fmaxf(bhi(u.w), 0.f); acc = fmaf(f, Ws[2 * i + 7][tx], acc);
    }
    Y[(size_t)r * NCLS + tx] = acc;
}

// propagation at width 16 (fp32)
__global__ __launch_bounds__(256) void k_agg16(const float* __restrict__ y16,
                                               const int* __restrict__ rowptr,
                                               const int* __restrict__ col,
                                               const float* __restrict__ val,
                                               const float* __restrict__ dis,
                                               const float* __restrict__ b2,
                                               float* __restrict__ out, int Nn) {
    int t = threadIdx.x;
    int tx = t & 15, ty = t >> 4;
    int d = blockIdx.x * 16 + ty;
    if (d >= Nn) return;
    int beg = rowptr[d], end = rowptr[d + 1];
    float acc = 0.f;
    for (int e = beg; e < end; ++e)
        acc = fmaf(val[e], y16[(size_t)col[e] * NCLS + tx], acc);
    float dd = dis[d];
    out[(size_t)d * NCLS + tx] = dd * acc + dd * dd * y16[(size_t)d * NCLS + tx] + b2[tx];
}

// ---------------------------------------------------------------------------
// softmax over axis 0
// ---------------------------------------------------------------------------
__global__ __launch_bounds__(256) void k_sm1(const float* __restrict__ z,
                                             float* __restrict__ pmax,
                                             float* __restrict__ psum, int Nn) {
    int b = blockIdx.x, t = threadIdx.x, tx = t & 15, ty = t >> 4;
    int CH = (Nn + 255) / 256;
    int r0 = b * CH, r1 = min(r0 + CH, Nn);
    __shared__ float red[16][17];
    __shared__ float gloc[16];
    float m = -3.4e38f;
    for (int r = r0 + ty; r < r1; r += 16) m = fmaxf(m, z[(size_t)r * NCLS + tx]);
    red[ty][tx] = m;
    __syncthreads();
    if (ty == 0) {
        float mm = red[0][tx];
#pragma unroll
        for (int i = 1; i < 16; ++i) mm = fmaxf(mm, red[i][tx]);
        gloc[tx] = mm;
    }
    __syncthreads();
    float g = gloc[tx];
    float s = 0.f;
    for (int r = r0 + ty; r < r1; r += 16) s += expf(z[(size_t)r * NCLS + tx] - g);
    red[ty][tx] = s;
    __syncthreads();
    if (ty == 0) {
        float ss = red[0][tx];
#pragma unroll
        for (int i = 1; i < 16; ++i) ss += red[i][tx];
        pmax[b * 16 + tx] = g;
        psum[b * 16 + tx] = ss;
    }
}

__global__ __launch_bounds__(256) void k_sm2(const float* __restrict__ pmax,
                                             const float* __restrict__ psum,
                                             float* __restrict__ g16,
                                             float* __restrict__ inv16) {
    int t = threadIdx.x, tx = t & 15, ty = t >> 4;
    __shared__ float red[16][17];
    __shared__ float gsh[16];
    float m = -3.4e38f;
    for (int b = ty; b < 256; b += 16) m = fmaxf(m, pmax[b * 16 + tx]);
    red[ty][tx] = m;
    __syncthreads();
    if (ty == 0) {
        float mm = red[0][tx];
#pragma unroll
        for (int i = 1; i < 16; ++i) mm = fmaxf(mm, red[i][tx]);
        gsh[tx] = mm;
    }
    __syncthreads();
    float g = gsh[tx];
    float s = 0.f;
    for (int b = ty; b < 256; b += 16)
        s += psum[b * 16 + tx] * expf(pmax[b * 16 + tx] - g);
    red[ty][tx] = s;
    __syncthreads();
    if (ty == 0) {
        float ss = red[0][tx];
#pragma unroll
        for (int i = 1; i < 16; ++i) ss += red[i][tx];
        g16[tx] = g;
        inv16[tx] = 1.0f / ss;
    }
}

__global__ void k_sm5(float* __restrict__ z, const float* __restrict__ g16,
                      const float* __restrict__ inv16, int total) {
    int i = blockIdx.x * 256 + threadIdx.x;
    if (i < total) {
        int c = i & 15;
        z[i] = expf(z[i] - g16[c]) * inv16[c];
    }
}

// ---------------------------------------------------------------------------
extern "C" void kernel_launch(void* const* d_in, const int* in_sizes, int n_in,
                              void* d_out, int out_size, void* d_ws, size_t ws_size,
                              hipStream_t stream) {
    const float* x  = (const float*)d_in[0];
    const int*   ei = (const int*)d_in[1];
    const float* W1 = (const float*)d_in[2];
    const float* b1 = (const float*)d_in[3];
    const float* Wi = (const float*)d_in[4];
    const float* bi = (const float*)d_in[5];
    const float* W2 = (const float*)d_in[6];
    const float* b2 = (const float*)d_in[7];
    float* out = (float*)d_out;

    int Nn = in_sizes[0] / NFEAT;   // 100000
    int E  = in_sizes[1] / 2;       // 1600000
    const int* esrc = ei;
    const int* edst = ei + E;

    char* p = (char*)d_ws;
    auto carve = [&](size_t bytes) -> char* {
        char* r = p;
        p += (bytes + 255) / 256 * 256;
        return r;
    };
    uint*  bufA    = (uint*) carve((size_t)Nn * 128 * 4);   // bf16 features
    uint*  bufB    = (uint*) carve((size_t)Nn * 128 * 4);
    int*   counts  = (int*)  carve((size_t)Nn * 4);
    int*   cursor  = (int*)  carve((size_t)Nn * 4);
    int*   rowptr  = (int*)  carve((size_t)(Nn + 1) * 4);
    float* dis     = (float*)carve((size_t)Nn * 4);
    int*   csr_col = (int*)  carve((size_t)E * 4);
    float* csr_val = (float*)carve((size_t)E * 4);
    float* y16     = (float*)carve((size_t)Nn * NCLS * 4);
    float* s1      = (float*)carve((size_t)Nn * 4);
    float* s2      = (float*)carve((size_t)Nn * 4);
    float* s3      = (float*)carve((size_t)Nn * 4);
    float* WA      = (float*)carve(256 * 256 * 4);
    float* WB      = (float*)carve(256 * 256 * 4);
    float* Wc      = (float*)carve(256 * 256 * 4);
    float* c1      = (float*)carve(256 * 4);
    float* c2      = (float*)carve(256 * 4);
    float* c3      = (float*)carve(256 * 4);
    float* u1      = (float*)carve(256 * 4);
    float* u2      = (float*)carve(256 * 4);
    float* pmax    = (float*)carve(256 * 16 * 4);
    float* psum    = (float*)carve(256 * 16 * 4);
    float* g16     = (float*)carve(16 * 4);
    float* inv16   = (float*)carve(16 * 4);

    hipMemsetAsync(counts, 0, (size_t)Nn * 4, stream);

    int gE = (E + 255) / 256;
    int gN = (Nn + 255) / 256;
    k_count<<<gE, 256, 0, stream>>>(edst, counts, E);
    k_dis<<<gN, 256, 0, stream>>>(counts, dis, Nn);
    k_scan<<<1, 256, 0, stream>>>(counts, rowptr, cursor, Nn);
    k_fill<<<gE, 256, 0, stream>>>(esrc, edst, dis, cursor, csr_col, csr_val, E);

    // weight chain: Wc = W1 Wi^3 ; c1 = b1 Wi^3, c2 = bi Wi^2, c3 = bi Wi, c4 = bi
    k_mm256<<<256, 256, 0, stream>>>(W1, Wi, WA);
    k_mm256<<<256, 256, 0, stream>>>(WA, Wi, WB);
    k_mm256<<<256, 256, 0, stream>>>(WB, Wi, Wc);
    k_vm256<<<1, 256, 0, stream>>>(bi, Wi, c3);
    k_vm256<<<1, 256, 0, stream>>>(c3, Wi, c2);
    k_vm256<<<1, 256, 0, stream>>>(b1, Wi, u1);
    k_vm256<<<1, 256, 0, stream>>>(u1, Wi, u2);
    k_vm256<<<1, 256, 0, stream>>>(u2, Wi, c1);

    // scalar propagation vectors s1 = A1, s2 = A^2 1, s3 = A^3 1
    k_svec<1><<<gN, 256, 0, stream>>>(nullptr, rowptr, csr_col, csr_val, dis, s1, Nn);
    k_svec<0><<<gN, 256, 0, stream>>>(s1, rowptr, csr_col, csr_val, dis, s2, Nn);
    k_svec<0><<<gN, 256, 0, stream>>>(s2, rowptr, csr_col, csr_val, dis, s3, Nn);

    // y0 = x @ Wc  (bf16 out)
    dim3 gg((Nn + 127) / 128, NFEAT / 128);
    gemm128b<<<gg, 256, 0, stream>>>(x, Wc, (ushort*)bufB, Nn);

    // h4 = A^4 y0 + rank-1 terms (in the last pass)
    k_aggb<0><<<Nn, 64, 0, stream>>>(bufB, rowptr, csr_col, csr_val, dis,
                                     nullptr, nullptr, nullptr, nullptr, nullptr, nullptr, nullptr, bufA);
    k_aggb<0><<<Nn, 64, 0, stream>>>(bufA, rowptr, csr_col, csr_val, dis,
                                     nullptr, nullptr, nullptr, nullptr, nullptr, nullptr, nullptr, bufB);
    k_aggb<0><<<Nn, 64, 0, stream>>>(bufB, rowptr, csr_col, csr_val, dis,
                                     nullptr, nullptr, nullptr, nullptr, nullptr, nullptr, nullptr, bufA);
    k_aggb<1><<<Nn, 64, 0, stream>>>(bufA, rowptr, csr_col, csr_val, dis,
                                     s1, s2, s3, c1, c2, c3, bi, bufB);

    // final: z = A(relu(h4) W2) + b2 ; softmax over nodes
    int g16b = (Nn + 15) / 16;
    k_gemm16b<<<g16b, 256, 0, stream>>>(bufB, W2, y16, Nn);
    k_agg16<<<g16b, 256, 0, stream>>>(y16, rowptr, csr_col, csr_val, dis, b2, out, Nn);

    k_sm1<<<256, 256, 0, stream>>>(out, pmax, psum, Nn);
    k_sm2<<<1, 256, 0, stream>>>(pmax, psum, g16, inv16);
    k_sm5<<<(Nn * NCLS + 255) / 256, 256, 0, stream>>>(out, g16, inv16, Nn * NCLS);
}

// Round 3
// 980.386 us; speedup vs baseline: 2.1890x; 1.3212x over previous
//
#include <hip/hip_runtime.h>
#include <cstdint>
#include <cstddef>

#define NFEAT 256
#define NCLS  16

typedef unsigned int uint;
typedef unsigned short ushort;
typedef __attribute__((ext_vector_type(8))) short short8;
typedef __attribute__((ext_vector_type(4))) float f32x4;

__device__ inline float blo(uint u) { return __uint_as_float(u << 16); }
__device__ inline float bhi(uint u) { return __uint_as_float(u & 0xffff0000u); }
__device__ inline ushort f2bf(float f) {
    uint b = __float_as_uint(f);
    b += 0x7fffu + ((b >> 16) & 1u);
    return (ushort)(b >> 16);
}
__device__ inline uint pack2(float a, float b) {
    return (uint)f2bf(a) | ((uint)f2bf(b) << 16);
}

// ---------------------------------------------------------------------------
// Graph build
// ---------------------------------------------------------------------------
__global__ void k_count(const int* __restrict__ dst, int* __restrict__ counts, int E) {
    int i = blockIdx.x * 256 + threadIdx.x;
    if (i < E) atomicAdd(&counts[dst[i]], 1);
}

__global__ void k_dis(const int* __restrict__ counts, float* __restrict__ dis, int Nn) {
    int i = blockIdx.x * 256 + threadIdx.x;
    if (i < Nn) dis[i] = rsqrtf((float)(counts[i] + 1));
}

// parallel scan, pass 1: per-block (256-wide) sums
__global__ __launch_bounds__(256) void k_bsum(const int* __restrict__ counts,
                                              int* __restrict__ bsum, int Nn) {
    int t = threadIdx.x, b = blockIdx.x;
    int i = b * 256 + t;
    int v = (i < Nn) ? counts[i] : 0;
    __shared__ int ps[256];
    ps[t] = v;
    __syncthreads();
    for (int off = 128; off > 0; off >>= 1) {
        if (t < off) ps[t] += ps[t + off];
        __syncthreads();
    }
    if (t == 0) bsum[b] = ps[0];
}

// pass 2: single block scans up to 512 block sums -> exclusive offsets
__global__ __launch_bounds__(256) void k_bscan(const int* __restrict__ bsum,
                                               int* __restrict__ boff,
                                               int nb, int* __restrict__ rowptr, int Nn) {
    int t = threadIdx.x;
    int v0 = (2 * t < nb) ? bsum[2 * t] : 0;
    int v1 = (2 * t + 1 < nb) ? bsum[2 * t + 1] : 0;
    int s = v0 + v1;
    __shared__ int ps[256];
    ps[t] = s;
    __syncthreads();
    for (int off = 1; off < 256; off <<= 1) {
        int v = (t >= off) ? ps[t - off] : 0;
        __syncthreads();
        ps[t] += v;
        __syncthreads();
    }
    int ex = ps[t] - s;
    boff[2 * t] = ex;
    boff[2 * t + 1] = ex + v0;
    if (t == 255) rowptr[Nn] = ps[255];
}

// pass 3: per-block exclusive scan + block offset -> rowptr & cursor
__global__ __launch_bounds__(256) void k_bwrite(const int* __restrict__ counts,
                                                const int* __restrict__ boff,
                                                int* __restrict__ rowptr,
                                                int* __restrict__ cursor, int Nn) {
    int t = threadIdx.x, b = blockIdx.x;
    int i = b * 256 + t;
    int v = (i < Nn) ? counts[i] : 0;
    __shared__ int ps[256];
    ps[t] = v;
    __syncthreads();
    for (int off = 1; off < 256; off <<= 1) {
        int u = (t >= off) ? ps[t - off] : 0;
        __syncthreads();
        ps[t] += u;
        __syncthreads();
    }
    int ex = ps[t] - v + boff[b];
    if (i < Nn) {
        rowptr[i] = ex;
        cursor[i] = ex;
    }
}

__global__ void k_fill(const int* __restrict__ src, const int* __restrict__ dst,
                       const float* __restrict__ dis, int* __restrict__ cursor,
                       int* __restrict__ csr_col, float* __restrict__ csr_val, int E) {
    int i = blockIdx.x * 256 + threadIdx.x;
    if (i < E) {
        int s = src[i], d = dst[i];
        int pos = atomicAdd(&cursor[d], 1);
        csr_col[pos] = s;
        csr_val[pos] = dis[s];
    }
}

// ---------------------------------------------------------------------------
// small dense helpers: 256x256 @ 256x256, and vec256 @ 256x256
// ---------------------------------------------------------------------------
__global__ __launch_bounds__(256) void k_mm256(const float* __restrict__ A,
                                               const float* __restrict__ B,
                                               float* __restrict__ C) {
    int i = blockIdx.x, j = threadIdx.x;
    float acc = 0.f;
    for (int k = 0; k < 256; ++k) acc = fmaf(A[i * 256 + k], B[k * 256 + j], acc);
    C[i * 256 + j] = acc;
}

__global__ __launch_bounds__(256) void k_vm256(const float* __restrict__ v,
                                               const float* __restrict__ M,
                                               float* __restrict__ r) {
    int j = threadIdx.x;
    float acc = 0.f;
    for (int k = 0; k < 256; ++k) acc = fmaf(v[k], M[(size_t)k * 256 + j], acc);
    r[j] = acc;
}

// pack Wc (fp32 [256][256]) into MFMA B-fragment layout, bf16.
// Wp word index: ((n16*8 + kstep)*64 + lane)*4 + w
// lane: n = n16*16 + (lane&15), kc = lane>>4; k = kstep*32 + kc*8 + 2w (+1 in hi)
__global__ __launch_bounds__(256) void k_pack(const float* __restrict__ W,
                                              uint* __restrict__ Wp) {
    int idx = blockIdx.x * 256 + threadIdx.x;   // 32768 words
    int w = idx & 3, lane = (idx >> 2) & 63, kstep = (idx >> 8) & 7, n16 = idx >> 11;
    int n = n16 * 16 + (lane & 15);
    int k = kstep * 32 + (lane >> 4) * 8 + 2 * w;
    Wp[idx] = pack2(W[k * 256 + n], W[(k + 1) * 256 + n]);
}

// ---------------------------------------------------------------------------
// MFMA GEMM: C[M,256](bf16) = A[M,256](fp32, converted on the fly) @ Wp(bf16 frags)
// block = 4 waves; wave computes 16 rows x 64 cols; grid (ceil(M/64), 4)
// ---------------------------------------------------------------------------
__global__ __launch_bounds__(256) void gemm_mfma(const float* __restrict__ A,
                                                 const uint* __restrict__ Wp,
                                                 ushort* __restrict__ C, int M) {
    int t = threadIdx.x;
    int wv = t >> 6;
    int l = t & 63;
    int m16 = l & 15;
    int kc = l >> 4;
    int bm = blockIdx.x * 64 + wv * 16;
    int bn = blockIdx.y * 64;
    int row = bm + m16;
    bool valid = row < M;
    const float* ap = A + (size_t)(valid ? row : 0) * 256 + kc * 8;
    const short8* wp = (const short8*)Wp;
    int n16b = bn >> 4;

    f32x4 acc0 = {0.f, 0.f, 0.f, 0.f};
    f32x4 acc1 = acc0, acc2 = acc0, acc3 = acc0;

#pragma unroll
    for (int ks = 0; ks < 8; ++ks) {
        float4 fa0 = make_float4(0.f, 0.f, 0.f, 0.f), fa1 = fa0;
        if (valid) {
            fa0 = *(const float4*)(ap + ks * 32);
            fa1 = *(const float4*)(ap + ks * 32 + 4);
        }
        short8 a;
        a[0] = (short)f2bf(fa0.x); a[1] = (short)f2bf(fa0.y);
        a[2] = (short)f2bf(fa0.z); a[3] = (short)f2bf(fa0.w);
        a[4] = (short)f2bf(fa1.x); a[5] = (short)f2bf(fa1.y);
        a[6] = (short)f2bf(fa1.z); a[7] = (short)f2bf(fa1.w);
        short8 b0 = wp[((n16b + 0) * 8 + ks) * 64 + l];
        short8 b1 = wp[((n16b + 1) * 8 + ks) * 64 + l];
        short8 b2 = wp[((n16b + 2) * 8 + ks) * 64 + l];
        short8 b3 = wp[((n16b + 3) * 8 + ks) * 64 + l];
        acc0 = __builtin_amdgcn_mfma_f32_16x16x32_bf16(a, b0, acc0, 0, 0, 0);
        acc1 = __builtin_amdgcn_mfma_f32_16x16x32_bf16(a, b1, acc1, 0, 0, 0);
        acc2 = __builtin_amdgcn_mfma_f32_16x16x32_bf16(a, b2, acc2, 0, 0, 0);
        acc3 = __builtin_amdgcn_mfma_f32_16x16x32_bf16(a, b3, acc3, 0, 0, 0);
    }

    // C/D layout: col = lane&15, row = (lane>>4)*4 + reg   [m89-verified]
#pragma unroll
    for (int r = 0; r < 4; ++r) {
        int orow = bm + kc * 4 + r;
        if (orow < M) {
            ushort* cp = C + (size_t)orow * 256 + bn + m16;
            cp[0]  = f2bf(acc0[r]);
            cp[16] = f2bf(acc1[r]);
            cp[32] = f2bf(acc2[r]);
            cp[48] = f2bf(acc3[r]);
        }
    }
}

// scalar propagation: sout = A_hat * sin   (FIRST: sin == ones)
template <int FIRST>
__global__ __launch_bounds__(256) void k_svec(const float* __restrict__ sin,
                                              const int* __restrict__ rowptr,
                                              const int* __restrict__ col,
                                              const float* __restrict__ val,
                                              const float* __restrict__ dis,
                                              float* __restrict__ sout, int Nn) {
    int d = blockIdx.x * 256 + threadIdx.x;
    if (d >= Nn) return;
    int beg = rowptr[d], end = rowptr[d + 1];
    float acc = 0.f;
    if (FIRST) {
        for (int e = beg; e < end; ++e) acc += val[e];
    } else {
        for (int e = beg; e < end; ++e) acc = fmaf(val[e], sin[col[e]], acc);
    }
    float dd = dis[d];
    sout[d] = fmaf(dd, acc, dd * dd * (FIRST ? 1.f : sin[d]));
}

// ---------------------------------------------------------------------------
// bf16 propagation: out[d] = bf16( dis_d*sum(val*y[col]) + dis_d^2*y[d] [+rank1] )
// 64 threads = 1 wave per node; thread owns 4 features (one uint2 = 4 bf16)
// ---------------------------------------------------------------------------
template <int FINAL>
__global__ __launch_bounds__(64) void k_aggb(const uint* __restrict__ y,
                                             const int* __restrict__ rowptr,
                                             const int* __restrict__ col,
                                             const float* __restrict__ val,
                                             const float* __restrict__ dis,
                                             const float* __restrict__ s1,
                                             const float* __restrict__ s2,
                                             const float* __restrict__ s3,
                                             const float* __restrict__ c1,
                                             const float* __restrict__ c2,
                                             const float* __restrict__ c3,
                                             const float* __restrict__ c4,
                                             uint* __restrict__ out) {
    int d = blockIdx.x;
    int t = threadIdx.x;
    const uint* yt = y + 2 * t;
    int beg = rowptr[d], end = rowptr[d + 1];
    float a0 = 0.f, a1 = 0.f, a2 = 0.f, a3 = 0.f;
    int e = beg;
    for (; e + 3 < end; e += 4) {
        int   cA = col[e],     cB = col[e + 1], cC = col[e + 2], cD = col[e + 3];
        float vA = val[e],     vB = val[e + 1], vC = val[e + 2], vD = val[e + 3];
        uint2 uA = *(const uint2*)(yt + (size_t)cA * 128);
        uint2 uB = *(const uint2*)(yt + (size_t)cB * 128);
        uint2 uC = *(const uint2*)(yt + (size_t)cC * 128);
        uint2 uD = *(const uint2*)(yt + (size_t)cD * 128);
        a0 = fmaf(vA, blo(uA.x), a0); a1 = fmaf(vA, bhi(uA.x), a1);
        a2 = fmaf(vA, blo(uA.y), a2); a3 = fmaf(vA, bhi(uA.y), a3);
        a0 = fmaf(vB, blo(uB.x), a0); a1 = fmaf(vB, bhi(uB.x), a1);
        a2 = fmaf(vB, blo(uB.y), a2); a3 = fmaf(vB, bhi(uB.y), a3);
        a0 = fmaf(vC, blo(uC.x), a0); a1 = fmaf(vC, bhi(uC.x), a1);
        a2 = fmaf(vC, blo(uC.y), a2); a3 = fmaf(vC, bhi(uC.y), a3);
        a0 = fmaf(vD, blo(uD.x), a0); a1 = fmaf(vD, bhi(uD.x), a1);
        a2 = fmaf(vD, blo(uD.y), a2); a3 = fmaf(vD, bhi(uD.y), a3);
    }
    for (; e < end; ++e) {
        int c = col[e]; float v = val[e];
        uint2 u = *(const uint2*)(yt + (size_t)c * 128);
        a0 = fmaf(v, blo(u.x), a0); a1 = fmaf(v, bhi(u.x), a1);
        a2 = fmaf(v, blo(u.y), a2); a3 = fmaf(v, bhi(u.y), a3);
    }
    float dd = dis[d];
    float d2 = dd * dd;
    uint2 us = *(const uint2*)(yt + (size_t)d * 128);
    float r0 = fmaf(dd, a0, d2 * blo(us.x));
    float r1 = fmaf(dd, a1, d2 * bhi(us.x));
    float r2 = fmaf(dd, a2, d2 * blo(us.y));
    float r3 = fmaf(dd, a3, d2 * bhi(us.y));
    if (FINAL) {
        float4 C1 = *(const float4*)(c1 + 4 * t);
        float4 C2 = *(const float4*)(c2 + 4 * t);
        float4 C3 = *(const float4*)(c3 + 4 * t);
        float4 C4 = *(const float4*)(c4 + 4 * t);
        float S1 = s1[d], S2 = s2[d], S3 = s3[d];
        r0 += S3 * C1.x + S2 * C2.x + S1 * C3.x + C4.x;
        r1 += S3 * C1.y + S2 * C2.y + S1 * C3.y + C4.y;
        r2 += S3 * C1.z + S2 * C2.z + S1 * C3.z + C4.z;
        r3 += S3 * C1.w + S2 * C2.w + S1 * C3.w + C4.w;
    }
    uint2 o;
    o.x = pack2(r0, r1);
    o.y = pack2(r2, r3);
    *(uint2*)(out + (size_t)d * 128 + 2 * t) = o;
}

// ---------------------------------------------------------------------------
// final layer: Y[M,16](f32) = relu(A[M,256](bf16)) @ W2[256,16](f32)
// ---------------------------------------------------------------------------
__global__ __launch_bounds__(256) void k_gemm16b(const uint* __restrict__ A,
                                                 const float* __restrict__ W2,
                                                 float* __restrict__ Y, int M) {
    __shared__ float Ws[256][16];
    int t = threadIdx.x;
    for (int i = t; i < 256 * 16; i += 256) Ws[i >> 4][i & 15] = W2[i];
    __syncthreads();
    int tx = t & 15, ty = t >> 4;
    int r = blockIdx.x * 16 + ty;
    if (r >= M) return;
    const uint* a = A + (size_t)r * 128;
    float acc = 0.f;
    for (int i = 0; i < 128; i += 4) {
        uint4 u = *(const uint4*)(a + i);
        float f;
        f = fmaxf(blo(u.x), 0.f); acc = fmaf(f, Ws[2 * i + 0][tx], acc);
        f = fmaxf(bhi(u.x), 0.f); acc = fmaf(f, Ws[2 * i + 1][tx], acc);
        f = fmaxf(blo(u.y), 0.f); acc = fmaf(f, Ws[2 * i + 2][tx], acc);
        f = fmaxf(bhi(u.y), 0.f); acc = fmaf(f, Ws[2 * i + 3][tx], acc);
        f = fmaxf(blo(u.z), 0.f); acc = fmaf(f, Ws[2 * i + 4][tx], acc);
        f = fmaxf(bhi(u.z), 0.f); acc = fmaf(f, Ws[2 * i + 5][tx], acc);
        f = fmaxf(blo(u.w), 0.f); acc = fmaf(f, Ws[2 * i + 6][tx], acc);
        f = fmaxf(bhi(u.w), 0.f); acc = fmaf(f, Ws[2 * i + 7][tx], acc);
    }
    Y[(size_t)r * NCLS + tx] = acc;
}

// propagation at width 16 (fp32)
__global__ __launch_bounds__(256) void k_agg16(const float* __restrict__ y16,
                                               const int* __restrict__ rowptr,
                                               const int* __restrict__ col,
                                               const float* __restrict__ val,
                                               const float* __restrict__ dis,
                                               const float* __restrict__ b2,
                                               float* __restrict__ out, int Nn) {
    int t = threadIdx.x;
    int tx = t & 15, ty = t >> 4;
    int d = blockIdx.x * 16 + ty;
    if (d >= Nn) return;
    int beg = rowptr[d], end = rowptr[d + 1];
    float acc = 0.f;
    for (int e = beg; e < end; ++e)
        acc = fmaf(val[e], y16[(size_t)col[e] * NCLS + tx], acc);
    float dd = dis[d];
    out[(size_t)d * NCLS + tx] = dd * acc + dd * dd * y16[(size_t)d * NCLS + tx] + b2[tx];
}

// ---------------------------------------------------------------------------
// softmax over axis 0
// ---------------------------------------------------------------------------
__global__ __launch_bounds__(256) void k_sm1(const float* __restrict__ z,
                                             float* __restrict__ pmax,
                                             float* __restrict__ psum, int Nn) {
    int b = blockIdx.x, t = threadIdx.x, tx = t & 15, ty = t >> 4;
    int CH = (Nn + 255) / 256;
    int r0 = b * CH, r1 = min(r0 + CH, Nn);
    __shared__ float red[16][17];
    __shared__ float gloc[16];
    float m = -3.4e38f;
    for (int r = r0 + ty; r < r1; r += 16) m = fmaxf(m, z[(size_t)r * NCLS + tx]);
    red[ty][tx] = m;
    __syncthreads();
    if (ty == 0) {
        float mm = red[0][tx];
#pragma unroll
        for (int i = 1; i < 16; ++i) mm = fmaxf(mm, red[i][tx]);
        gloc[tx] = mm;
    }
    __syncthreads();
    float g = gloc[tx];
    float s = 0.f;
    for (int r = r0 + ty; r < r1; r += 16) s += expf(z[(size_t)r * NCLS + tx] - g);
    red[ty][tx] = s;
    __syncthreads();
    if (ty == 0) {
        float ss = red[0][tx];
#pragma unroll
        for (int i = 1; i < 16; ++i) ss += red[i][tx];
        pmax[b * 16 + tx] = g;
        psum[b * 16 + tx] = ss;
    }
}

__global__ __launch_bounds__(256) void k_sm2(const float* __restrict__ pmax,
                                             const float* __restrict__ psum,
                                             float* __restrict__ g16,
                                             float* __restrict__ inv16) {
    int t = threadIdx.x, tx = t & 15, ty = t >> 4;
    __shared__ float red[16][17];
    __shared__ float gsh[16];
    float m = -3.4e38f;
    for (int b = ty; b < 256; b += 16) m = fmaxf(m, pmax[b * 16 + tx]);
    red[ty][tx] = m;
    __syncthreads();
    if (ty == 0) {
        float mm = red[0][tx];
#pragma unroll
        for (int i = 1; i < 16; ++i) mm = fmaxf(mm, red[i][tx]);
        gsh[tx] = mm;
    }
    __syncthreads();
    float g = gsh[tx];
    float s = 0.f;
    for (int b = ty; b < 256; b += 16)
        s += psum[b * 16 + tx] * expf(pmax[b * 16 + tx] - g);
    red[ty][tx] = s;
    __syncthreads();
    if (ty == 0) {
        float ss = red[0][tx];
#pragma unroll
        for (int i = 1; i < 16; ++i) ss += red[i][tx];
        g16[tx] = g;
        inv16[tx] = 1.0f / ss;
    }
}

__global__ void k_sm5(float* __restrict__ z, const float* __restrict__ g16,
                      const float* __restrict__ inv16, int total) {
    int i = blockIdx.x * 256 + threadIdx.x;
    if (i < total) {
        int c = i & 15;
        z[i] = expf(z[i] - g16[c]) * inv16[c];
    }
}

// ---------------------------------------------------------------------------
extern "C" void kernel_launch(void* const* d_in, const int* in_sizes, int n_in,
                              void* d_out, int out_size, void* d_ws, size_t ws_size,
                              hipStream_t stream) {
    const float* x  = (const float*)d_in[0];
    const int*   ei = (const int*)d_in[1];
    const float* W1 = (const float*)d_in[2];
    const float* b1 = (const float*)d_in[3];
    const float* Wi = (const float*)d_in[4];
    const float* bi = (const float*)d_in[5];
    const float* W2 = (const float*)d_in[6];
    const float* b2 = (const float*)d_in[7];
    float* out = (float*)d_out;

    int Nn = in_sizes[0] / NFEAT;   // 100000
    int E  = in_sizes[1] / 2;       // 1600000
    const int* esrc = ei;
    const int* edst = ei + E;

    char* p = (char*)d_ws;
    auto carve = [&](size_t bytes) -> char* {
        char* r = p;
        p += (bytes + 255) / 256 * 256;
        return r;
    };
    uint*  bufA    = (uint*) carve((size_t)Nn * 128 * 4);   // bf16 features
    uint*  bufB    = (uint*) carve((size_t)Nn * 128 * 4);
    int*   counts  = (int*)  carve((size_t)Nn * 4);
    int*   cursor  = (int*)  carve((size_t)Nn * 4);
    int*   rowptr  = (int*)  carve((size_t)(Nn + 1) * 4);
    float* dis     = (float*)carve((size_t)Nn * 4);
    int*   csr_col = (int*)  carve((size_t)E * 4);
    float* csr_val = (float*)carve((size_t)E * 4);
    float* y16     = (float*)carve((size_t)Nn * NCLS * 4);
    float* s1      = (float*)carve((size_t)Nn * 4);
    float* s2      = (float*)carve((size_t)Nn * 4);
    float* s3      = (float*)carve((size_t)Nn * 4);
    float* WA      = (float*)carve(256 * 256 * 4);
    float* WB      = (float*)carve(256 * 256 * 4);
    float* Wc      = (float*)carve(256 * 256 * 4);
    uint*  Wp      = (uint*) carve(32768 * 4);
    float* c1      = (float*)carve(256 * 4);
    float* c2      = (float*)carve(256 * 4);
    float* c3      = (float*)carve(256 * 4);
    float* u1      = (float*)carve(256 * 4);
    float* u2      = (float*)carve(256 * 4);
    int*   bsum    = (int*)  carve(512 * 4);
    int*   boff    = (int*)  carve(512 * 4);
    float* pmax    = (float*)carve(256 * 16 * 4);
    float* psum    = (float*)carve(256 * 16 * 4);
    float* g16     = (float*)carve(16 * 4);
    float* inv16   = (float*)carve(16 * 4);

    hipMemsetAsync(counts, 0, (size_t)Nn * 4, stream);

    int gE = (E + 255) / 256;
    int gN = (Nn + 255) / 256;
    k_count<<<gE, 256, 0, stream>>>(edst, counts, E);
    k_dis<<<gN, 256, 0, stream>>>(counts, dis, Nn);
    k_bsum<<<gN, 256, 0, stream>>>(counts, bsum, Nn);
    k_bscan<<<1, 256, 0, stream>>>(bsum, boff, gN, rowptr, Nn);
    k_bwrite<<<gN, 256, 0, stream>>>(counts, boff, rowptr, cursor, Nn);
    k_fill<<<gE, 256, 0, stream>>>(esrc, edst, dis, cursor, csr_col, csr_val, E);

    // weight chain: Wc = W1 Wi^3 ; c1 = b1 Wi^3, c2 = bi Wi^2, c3 = bi Wi, c4 = bi
    k_mm256<<<256, 256, 0, stream>>>(W1, Wi, WA);
    k_mm256<<<256, 256, 0, stream>>>(WA, Wi, WB);
    k_mm256<<<256, 256, 0, stream>>>(WB, Wi, Wc);
    k_pack<<<128, 256, 0, stream>>>(Wc, Wp);
    k_vm256<<<1, 256, 0, stream>>>(bi, Wi, c3);
    k_vm256<<<1, 256, 0, stream>>>(c3, Wi, c2);
    k_vm256<<<1, 256, 0, stream>>>(b1, Wi, u1);
    k_vm256<<<1, 256, 0, stream>>>(u1, Wi, u2);
    k_vm256<<<1, 256, 0, stream>>>(u2, Wi, c1);

    // scalar propagation vectors s1 = A1, s2 = A^2 1, s3 = A^3 1
    k_svec<1><<<gN, 256, 0, stream>>>(nullptr, rowptr, csr_col, csr_val, dis, s1, Nn);
    k_svec<0><<<gN, 256, 0, stream>>>(s1, rowptr, csr_col, csr_val, dis, s2, Nn);
    k_svec<0><<<gN, 256, 0, stream>>>(s2, rowptr, csr_col, csr_val, dis, s3, Nn);

    // y0 = x @ Wc  (bf16 out, MFMA)
    dim3 gg((Nn + 63) / 64, 4);
    gemm_mfma<<<gg, 256, 0, stream>>>(x, Wp, (ushort*)bufB, Nn);

    // h4 = A^4 y0 + rank-1 terms (in the last pass)
    k_aggb<0><<<Nn, 64, 0, stream>>>(bufB, rowptr, csr_col, csr_val, dis,
                                     nullptr, nullptr, nullptr, nullptr, nullptr, nullptr, nullptr, bufA);
    k_aggb<0><<<Nn, 64, 0, stream>>>(bufA, rowptr, csr_col, csr_val, dis,
                                     nullptr, nullptr, nullptr, nullptr, nullptr, nullptr, nullptr, bufB);
    k_aggb<0><<<Nn, 64, 0, stream>>>(bufB, rowptr, csr_col, csr_val, dis,
                                     nullptr, nullptr, nullptr, nullptr, nullptr, nullptr, nullptr, bufA);
    k_aggb<1><<<Nn, 64, 0, stream>>>(bufA, rowptr, csr_col, csr_val, dis,
                                     s1, s2, s3, c1, c2, c3, bi, bufB);

    // final: z = A(relu(h4) W2) + b2 ; softmax over nodes
    int g16b = (Nn + 15) / 16;
    k_gemm16b<<<g16b, 256, 0, stream>>>(bufB, W2, y16, Nn);
    k_agg16<<<g16b, 256, 0, stream>>>(y16, rowptr, csr_col, csr_val, dis, b2, out, Nn);

    k_sm1<<<256, 256, 0, stream>>>(out, pmax, psum, Nn);
    k_sm2<<<1, 256, 0, stream>>>(pmax, psum, g16, inv16);
    k_sm5<<<(Nn * NCLS + 255) / 256, 256, 0, stream>>>(out, g16, inv16, Nn * NCLS);
}